// Round 1
// baseline (308.780 us; speedup 1.0000x reference)
//
#include <hip/hip_runtime.h>

#define BQ   8
#define CIN  64
#define HH   128
#define WW   128
#define COUT 64
#define K2   9

typedef __attribute__((ext_vector_type(8))) short bf16x8;
typedef __attribute__((ext_vector_type(4))) float f32x4;

__device__ __forceinline__ unsigned short f2bf(float f) {
    unsigned int u = __float_as_uint(f);
    u += 0x7fff + ((u >> 16) & 1);   // round-to-nearest-even
    return (unsigned short)(u >> 16);
}

// weight fp32 [o][c][kh][kw] -> bf16 [o][k*64 + c]  (B^T layout, K-contiguous)
__global__ void wprep_kernel(const float* __restrict__ w, unsigned short* __restrict__ wt) {
    int idx = blockIdx.x * 256 + threadIdx.x;
    if (idx >= COUT * CIN * K2) return;
    int o = idx / (CIN * K2);
    int r = idx % (CIN * K2);
    int k = r / CIN;
    int c = r % CIN;
    wt[idx] = f2bf(w[o * (CIN * K2) + c * K2 + k]);
}

__launch_bounds__(256)
__global__ void dcn_kernel(const float* __restrict__ x,
                           const float* __restrict__ off,
                           const unsigned short* __restrict__ wt,
                           float* __restrict__ out) {
    // s[pix][c] bf16, row stride 66 elems = 132 B = 33 dwords -> write bank = lane%32 (conflict-free)
    __shared__ unsigned short s_s[64 * 66];

    const int tid = threadIdx.x;
    const int w   = tid >> 6;     // wave 0..3
    const int l   = tid & 63;     // lane

    const int bid = blockIdx.x;
    const int b   = bid >> 8;          // 256 tiles per batch
    const int t   = bid & 255;
    const int ty0 = (t >> 4) << 3;
    const int tx0 = (t & 15) << 3;

    // sampling: lane = pixel of the 8x8 tile
    const int iy = l >> 3, ix = l & 7;
    const int ypix = ty0 + iy, xpix = tx0 + ix;

    f32x4 acc[4] = {{0,0,0,0},{0,0,0,0},{0,0,0,0},{0,0,0,0}};

    const int c0w = w * 16;            // this wave's channel range for sampling

    for (int k = 0; k < K2; ++k) {
        // ---------------- sampling phase: s[pix][c] for this kernel tap ----------------
        float dy = off[(((b * (2 * K2)) + 2 * k    ) * HH + ypix) * WW + xpix];
        float dx = off[(((b * (2 * K2)) + 2 * k + 1) * HH + ypix) * WW + xpix];
        float py = dy + (float)(k / 3 + ypix - 1);
        float px = dx + (float)(k % 3 + xpix - 1);
        float fy = floorf(py), fx = floorf(px);
        float wy = py - fy,    wx = px - fx;
        int y0 = (int)fy, x0 = (int)fx;

        int   yc0 = min(max(y0,     0), HH - 1);
        int   yc1 = min(max(y0 + 1, 0), HH - 1);
        float ay0 = (y0 >= 0  && y0 <= HH - 1) ? (1.f - wy) : 0.f;
        float ay1 = (y0 >= -1 && y0 <= HH - 2) ? wy         : 0.f;

        int   xL  = min(max(x0, 0), WW - 2);      // load columns xL, xL+1
        float bx0 = (x0 >= 0  && x0 <= WW - 1) ? (1.f - wx) : 0.f;
        float bx1 = (x0 >= -1 && x0 <= WW - 2) ? wx         : 0.f;
        bool  sw  = (x0 != xL);                   // corner0 maps to elem1 when clamped
        float wxa = sw ? bx1 : bx0;               // weight on column xL
        float wxb = sw ? bx0 : bx1;               // weight on column xL+1
        float W0x = ay0 * wxa, W0y = ay0 * wxb;
        float W1x = ay1 * wxa, W1y = ay1 * wxb;

        const float* r0 = x + ((b * CIN + c0w) * HH + yc0) * WW + xL;
        const float* r1 = x + ((b * CIN + c0w) * HH + yc1) * WW + xL;
        unsigned short* sd = &s_s[l * 66 + c0w];
        #pragma unroll
        for (int cc = 0; cc < 16; ++cc) {
            float v = W0x * r0[0] + W0y * r0[1] + W1x * r1[0] + W1y * r1[1];
            sd[cc] = f2bf(v);
            r0 += HH * WW;
            r1 += HH * WW;
        }
        __syncthreads();

        // ---------------- MFMA phase: C[16 pix][64 o] += A[16][64] * B[64][64] --------
        const int o_lane = l & 15;
        const int q      = l >> 4;
        #pragma unroll
        for (int ks = 0; ks < 2; ++ks) {
            const int cb  = ks * 32 + q * 8;          // k-offset within chunk for this lane
            const int row = w * 16 + o_lane;          // pixel row (A operand, M side)
            const unsigned int* sp = (const unsigned int*)s_s;
            const int ib = row * 33 + (cb >> 1);
            union { unsigned int u[4]; bf16x8 v; } af;
            af.u[0] = sp[ib];     af.u[1] = sp[ib + 1];
            af.u[2] = sp[ib + 2]; af.u[3] = sp[ib + 3];
            #pragma unroll
            for (int nt = 0; nt < 4; ++nt) {
                const int o   = nt * 16 + o_lane;
                const int ckT = k * 64 + cb;
                bf16x8 bfv = *(const bf16x8*)(wt + o * (CIN * K2) + ckT);
                acc[nt] = __builtin_amdgcn_mfma_f32_16x16x32_bf16(af.v, bfv, acc[nt], 0, 0, 0);
            }
        }
        __syncthreads();
    }

    // ---------------- epilogue: C/D layout col=lane&15 (=o), row=(lane>>4)*4+j (=pix) --
    const int o_lane = l & 15;
    const int rq     = (l >> 4) * 4;
    #pragma unroll
    for (int nt = 0; nt < 4; ++nt) {
        const int o = nt * 16 + o_lane;
        #pragma unroll
        for (int j = 0; j < 4; ++j) {
            const int pix = w * 16 + rq + j;
            const int yy  = ty0 + (pix >> 3);
            const int xx  = tx0 + (pix & 7);
            out[(((size_t)b * COUT + o) * HH + yy) * WW + xx] = acc[nt][j];
        }
    }
}

extern "C" void kernel_launch(void* const* d_in, const int* in_sizes, int n_in,
                              void* d_out, int out_size, void* d_ws, size_t ws_size,
                              hipStream_t stream) {
    const float* x   = (const float*)d_in[0];
    const float* off = (const float*)d_in[1];
    const float* wgt = (const float*)d_in[2];
    float* out = (float*)d_out;
    unsigned short* wt = (unsigned short*)d_ws;   // 73728 B of scratch

    wprep_kernel<<<(COUT * CIN * K2 + 255) / 256, 256, 0, stream>>>(wgt, wt);
    dcn_kernel<<<2048, 256, 0, stream>>>(x, off, wt, out);
}

// Round 2
// 82.557 us; speedup vs baseline: 3.7402x; 3.7402x over previous
//
#include <hip/hip_runtime.h>

#define CIN  64
#define HH   128
#define WW   128
#define COUT 64
#define K2   9

typedef __attribute__((ext_vector_type(8))) short bf16x8;
typedef __attribute__((ext_vector_type(4))) float f32x4;
typedef __attribute__((ext_vector_type(4))) unsigned short u16x4;

__device__ __forceinline__ unsigned short f2bf(float f) {
    unsigned int u = __float_as_uint(f);
    u += 0x7fff + ((u >> 16) & 1);   // RNE
    return (unsigned short)(u >> 16);
}
__device__ __forceinline__ float bf2f(unsigned short s) {
    return __uint_as_float(((unsigned int)s) << 16);
}

// ---------------- prep: x fp32 NCHW -> bf16 NHWC ----------------
__launch_bounds__(256)
__global__ void xprep_kernel(const float* __restrict__ x, unsigned short* __restrict__ xt) {
    __shared__ float sT[64][67];          // stride 67: conflict-free both phases
    const int t   = threadIdx.x;
    const int bid = blockIdx.x;           // b*256 + y*2 + xc
    const int b   = bid >> 8;
    const int y   = (bid >> 1) & 127;
    const int x0  = (bid & 1) << 6;
    const int lane = t & 63;
    const int cg   = t >> 6;              // 0..3
    #pragma unroll
    for (int cc = 0; cc < 16; ++cc) {
        int c = cg * 16 + cc;
        sT[lane][c] = x[(((b * CIN + c) * HH) + y) * WW + x0 + lane];
    }
    __syncthreads();
    const int xi = t >> 2;
    const int c0 = (t & 3) * 16;
    union { unsigned short s[16]; bf16x8 v[2]; } u;
    #pragma unroll
    for (int j = 0; j < 16; ++j) u.s[j] = f2bf(sT[xi][c0 + j]);
    unsigned short* dst = xt + ((((size_t)b * HH + y) * WW) + x0 + xi) * 64 + c0;
    *(bf16x8*)(dst)     = u.v[0];
    *(bf16x8*)(dst + 8) = u.v[1];
}

// ---------------- prep: weight fp32 [o][c][k] -> bf16 MFMA-B-fragment order ----------------
// wtp[ ((k*2+ks)*4+nt)*64*8 + l*8 + j ] = W[o=nt*16+(l&15)][c=ks*32+(l>>4)*8+j][k]
__global__ void wprep_kernel(const float* __restrict__ w, unsigned short* __restrict__ wtp) {
    int idx = blockIdx.x * 256 + threadIdx.x;
    if (idx >= COUT * CIN * K2) return;
    int j  = idx & 7;
    int l  = (idx >> 3) & 63;
    int nt = (idx >> 9) & 3;
    int ks = (idx >> 11) & 1;
    int k  = idx >> 12;                       // 0..8
    int o  = nt * 16 + (l & 15);
    int c  = ks * 32 + (l >> 4) * 8 + j;
    wtp[idx] = f2bf(w[(o * CIN + c) * K2 + k]);
}

// ---------------- main: fused deformable im2col (coalesced NHWC gather) + MFMA ----------------
__launch_bounds__(256)
__global__ void dcn_kernel(const unsigned short* __restrict__ xt,
                           const float* __restrict__ off,
                           const unsigned short* __restrict__ wtp,
                           float* __restrict__ out) {
    __shared__ unsigned short s_s[64 * 68];   // s[pix][c], row stride 68 (136 B, 8B-aligned)

    const int tid = threadIdx.x;
    const int w   = tid >> 6;                 // wave 0..3
    const int l   = tid & 63;

    int bid = blockIdx.x;
    bid = (bid & 7) * 256 + (bid >> 3);       // XCD swizzle: one batch per XCD (grid=2048)
    const int b   = bid >> 8;
    const int t   = bid & 255;
    const int ty0 = (t >> 4) << 3;
    const int tx0 = (t & 15) << 3;

    const int g      = l >> 4;                // 16-lane pixel subgroup
    const int lane16 = l & 15;                // channel quad index

    f32x4 acc[4] = {{0,0,0,0},{0,0,0,0},{0,0,0,0},{0,0,0,0}};

    const float* offb = off + (size_t)b * (2 * K2) * HH * WW;
    const unsigned short* xb = xt + (size_t)b * HH * WW * 64;

    for (int k = 0; k < K2; ++k) {
        // WAR: previous tap's LDS reads done before overwriting (wave-local)
        asm volatile("s_waitcnt lgkmcnt(0)" ::: "memory");
        const int kdy = k / 3 - 1, kdx = k % 3 - 1;
        #pragma unroll
        for (int it = 0; it < 4; ++it) {
            const int pix  = w * 16 + it * 4 + g;
            const int ypix = ty0 + (pix >> 3);
            const int xpix = tx0 + (pix & 7);
            float dy = offb[((2 * k    ) * HH + ypix) * WW + xpix];
            float dx = offb[((2 * k + 1) * HH + ypix) * WW + xpix];
            float py = dy + (float)(ypix + kdy);
            float px = dx + (float)(xpix + kdx);
            float fy = floorf(py), fx = floorf(px);
            float wy = py - fy,    wx = px - fx;
            int y0  = (int)fy, x0i = (int)fx;
            int yc0 = min(max(y0,     0), HH - 1);
            int yc1 = min(max(y0 + 1, 0), HH - 1);
            float ay0 = (y0 >= 0  && y0 <= HH - 1) ? (1.f - wy) : 0.f;
            float ay1 = (y0 >= -1 && y0 <= HH - 2) ? wy         : 0.f;
            int   xL  = min(max(x0i, 0), WW - 2);
            float bx0 = (x0i >= 0  && x0i <= WW - 1) ? (1.f - wx) : 0.f;
            float bx1 = (x0i >= -1 && x0i <= WW - 2) ? wx         : 0.f;
            bool  sw  = (x0i != xL);
            float wxa = sw ? bx1 : bx0;
            float wxb = sw ? bx0 : bx1;
            float W00 = ay0 * wxa, W01 = ay0 * wxb;
            float W10 = ay1 * wxa, W11 = ay1 * wxb;

            const unsigned short* p0 = xb + ((yc0 * WW) + xL) * 64 + 4 * lane16;
            const unsigned short* p1 = xb + ((yc1 * WW) + xL) * 64 + 4 * lane16;
            u16x4 u00 = *(const u16x4*)p0;
            u16x4 u01 = *(const u16x4*)(p0 + 64);
            u16x4 u10 = *(const u16x4*)p1;
            u16x4 u11 = *(const u16x4*)(p1 + 64);
            unsigned short r[4];
            #pragma unroll
            for (int j = 0; j < 4; ++j) {
                float v = W00 * bf2f(u00[j]) + W01 * bf2f(u01[j])
                        + W10 * bf2f(u10[j]) + W11 * bf2f(u11[j]);
                r[j] = f2bf(v);
            }
            *(u16x4*)(&s_s[pix * 68 + 4 * lane16]) = *(const u16x4*)r;   // 8B ds_write
        }
        // RAW: this wave's LDS writes complete before cross-lane reads (wave-local)
        asm volatile("s_waitcnt lgkmcnt(0)" ::: "memory");

        const int row = w * 16 + lane16;      // A: row=pixel, lane needs k-slice g*8..g*8+7
        #pragma unroll
        for (int ks = 0; ks < 2; ++ks) {
            const unsigned short* ap = &s_s[row * 68 + ks * 32 + g * 8];
            union { u16x4 h[2]; bf16x8 v; } af;
            af.h[0] = *(const u16x4*)ap;
            af.h[1] = *(const u16x4*)(ap + 4);
            #pragma unroll
            for (int nt = 0; nt < 4; ++nt) {
                bf16x8 bv = *(const bf16x8*)(wtp + (((k * 2 + ks) * 4 + nt) * 64 + l) * 8);
                acc[nt] = __builtin_amdgcn_mfma_f32_16x16x32_bf16(af.v, bv, acc[nt], 0, 0, 0);
            }
        }
    }

    // epilogue: C/D layout col=lane&15 (=o), row=(lane>>4)*4+j (=pix)
    const int o_lane = l & 15;
    const int rq     = (l >> 4) * 4;
    #pragma unroll
    for (int nt = 0; nt < 4; ++nt) {
        const int o = nt * 16 + o_lane;
        #pragma unroll
        for (int j = 0; j < 4; ++j) {
            const int pix = w * 16 + rq + j;
            const int yy  = ty0 + (pix >> 3);
            const int xx  = tx0 + (pix & 7);
            out[(((size_t)b * COUT + o) * HH + yy) * WW + xx] = acc[nt][j];
        }
    }
}

// ---------------- fallback path (R0 kernel) if ws_size can't hold xt ----------------
__global__ void wprep_fb(const float* __restrict__ w, unsigned short* __restrict__ wt) {
    int idx = blockIdx.x * 256 + threadIdx.x;
    if (idx >= COUT * CIN * K2) return;
    int o = idx / (CIN * K2);
    int r = idx % (CIN * K2);
    int k = r / CIN;
    int c = r % CIN;
    wt[idx] = f2bf(w[o * (CIN * K2) + c * K2 + k]);
}

__launch_bounds__(256)
__global__ void dcn_fb(const float* __restrict__ x, const float* __restrict__ off,
                       const unsigned short* __restrict__ wt, float* __restrict__ out) {
    __shared__ unsigned short s_s[64 * 66];
    const int tid = threadIdx.x;
    const int w = tid >> 6, l = tid & 63;
    const int bid = blockIdx.x;
    const int b = bid >> 8, t = bid & 255;
    const int ty0 = (t >> 4) << 3, tx0 = (t & 15) << 3;
    const int iy = l >> 3, ix = l & 7;
    const int ypix = ty0 + iy, xpix = tx0 + ix;
    f32x4 acc[4] = {{0,0,0,0},{0,0,0,0},{0,0,0,0},{0,0,0,0}};
    const int c0w = w * 16;
    for (int k = 0; k < K2; ++k) {
        float dy = off[(((b * (2*K2)) + 2*k    ) * HH + ypix) * WW + xpix];
        float dx = off[(((b * (2*K2)) + 2*k + 1) * HH + ypix) * WW + xpix];
        float py = dy + (float)(k / 3 + ypix - 1);
        float px = dx + (float)(k % 3 + xpix - 1);
        float fy = floorf(py), fx = floorf(px);
        float wy = py - fy, wx = px - fx;
        int y0 = (int)fy, x0 = (int)fx;
        int yc0 = min(max(y0, 0), HH-1), yc1 = min(max(y0+1, 0), HH-1);
        float ay0 = (y0 >= 0 && y0 <= HH-1) ? (1.f-wy) : 0.f;
        float ay1 = (y0 >= -1 && y0 <= HH-2) ? wy : 0.f;
        int xL = min(max(x0, 0), WW-2);
        float bx0 = (x0 >= 0 && x0 <= WW-1) ? (1.f-wx) : 0.f;
        float bx1 = (x0 >= -1 && x0 <= WW-2) ? wx : 0.f;
        bool sw = (x0 != xL);
        float wxa = sw ? bx1 : bx0, wxb = sw ? bx0 : bx1;
        float W0x = ay0*wxa, W0y = ay0*wxb, W1x = ay1*wxa, W1y = ay1*wxb;
        const float* r0 = x + ((b * CIN + c0w) * HH + yc0) * WW + xL;
        const float* r1 = x + ((b * CIN + c0w) * HH + yc1) * WW + xL;
        unsigned short* sd = &s_s[l * 66 + c0w];
        #pragma unroll
        for (int cc = 0; cc < 16; ++cc) {
            sd[cc] = f2bf(W0x*r0[0] + W0y*r0[1] + W1x*r1[0] + W1y*r1[1]);
            r0 += HH*WW; r1 += HH*WW;
        }
        __syncthreads();
        const int o_lane = l & 15, q = l >> 4;
        #pragma unroll
        for (int ks = 0; ks < 2; ++ks) {
            const int cb = ks*32 + q*8;
            const int row = w*16 + o_lane;
            const unsigned int* sp = (const unsigned int*)s_s;
            const int ib = row*33 + (cb >> 1);
            union { unsigned int u[4]; bf16x8 v; } af;
            af.u[0]=sp[ib]; af.u[1]=sp[ib+1]; af.u[2]=sp[ib+2]; af.u[3]=sp[ib+3];
            #pragma unroll
            for (int nt = 0; nt < 4; ++nt) {
                bf16x8 bfv = *(const bf16x8*)(wt + (nt*16 + o_lane) * (CIN*K2) + k*64 + cb);
                acc[nt] = __builtin_amdgcn_mfma_f32_16x16x32_bf16(af.v, bfv, acc[nt], 0, 0, 0);
            }
        }
        __syncthreads();
    }
    const int o_lane = l & 15, rq = (l >> 4) * 4;
    #pragma unroll
    for (int nt = 0; nt < 4; ++nt) {
        const int o = nt*16 + o_lane;
        #pragma unroll
        for (int j = 0; j < 4; ++j) {
            const int pix = w*16 + rq + j;
            out[(((size_t)b * COUT + o) * HH + ty0 + (pix>>3)) * WW + tx0 + (pix&7)] = acc[nt][j];
        }
    }
}

extern "C" void kernel_launch(void* const* d_in, const int* in_sizes, int n_in,
                              void* d_out, int out_size, void* d_ws, size_t ws_size,
                              hipStream_t stream) {
    const float* x   = (const float*)d_in[0];
    const float* off = (const float*)d_in[1];
    const float* wgt = (const float*)d_in[2];
    float* out = (float*)d_out;

    const size_t xt_bytes = (size_t)8 * HH * WW * 64 * sizeof(unsigned short); // 16 MiB
    const size_t wt_bytes = (size_t)COUT * CIN * K2 * sizeof(unsigned short);  // 72 KiB

    if (ws_size >= xt_bytes + wt_bytes) {
        unsigned short* xt  = (unsigned short*)d_ws;
        unsigned short* wtp = (unsigned short*)((char*)d_ws + xt_bytes);
        xprep_kernel<<<2048, 256, 0, stream>>>(x, xt);
        wprep_kernel<<<(COUT * CIN * K2 + 255) / 256, 256, 0, stream>>>(wgt, wtp);
        dcn_kernel<<<2048, 256, 0, stream>>>(xt, off, wtp, out);
    } else {
        unsigned short* wt = (unsigned short*)d_ws;
        wprep_fb<<<(COUT * CIN * K2 + 255) / 256, 256, 0, stream>>>(wgt, wt);
        dcn_fb<<<2048, 256, 0, stream>>>(x, off, wt, out);
    }
}

// Round 3
// 76.663 us; speedup vs baseline: 4.0278x; 1.0769x over previous
//
#include <hip/hip_runtime.h>
#include <hip/hip_bf16.h>

#define CIN  64
#define HH   128
#define WW   128
#define COUT 64
#define K2   9
#define HW   (HH * WW)

typedef __attribute__((ext_vector_type(8))) short bf16x8;
typedef __attribute__((ext_vector_type(4))) float f32x4;
typedef __attribute__((ext_vector_type(2))) float f32x2;
typedef __attribute__((ext_vector_type(4))) unsigned short u16x4;
typedef __attribute__((ext_vector_type(2))) int i32x2;

__device__ __forceinline__ unsigned short f2bf(float f) {
    __hip_bfloat16 h = __float2bfloat16(f);
    return *reinterpret_cast<unsigned short*>(&h);
}
__device__ __forceinline__ float bf2f(unsigned short s) {
    return __uint_as_float(((unsigned int)s) << 16);
}
// unpack dword holding 2 bf16 (lo=ch0, hi=ch1) -> f32x2
__device__ __forceinline__ f32x2 up2(unsigned int d) {
    f32x2 r;
    r[0] = __uint_as_float(d << 16);
    r[1] = __uint_as_float(d & 0xffff0000u);
    return r;
}

// ---------------- prep: x fp32 NCHW -> bf16 NHWC ----------------
__launch_bounds__(256)
__global__ void xprep_kernel(const float* __restrict__ x, unsigned short* __restrict__ xt) {
    __shared__ float sT[64][67];
    const int t   = threadIdx.x;
    const int bid = blockIdx.x;           // b*256 + y*2 + xc
    const int b   = bid >> 8;
    const int y   = (bid >> 1) & 127;
    const int x0  = (bid & 1) << 6;
    const int lane = t & 63;
    const int cg   = t >> 6;
    #pragma unroll
    for (int cc = 0; cc < 16; ++cc) {
        int c = cg * 16 + cc;
        sT[lane][c] = x[(((b * CIN + c) * HH) + y) * WW + x0 + lane];
    }
    __syncthreads();
    const int xi = t >> 2;
    const int c0 = (t & 3) * 16;
    union { unsigned short s[16]; bf16x8 v[2]; } u;
    #pragma unroll
    for (int j = 0; j < 16; ++j) u.s[j] = f2bf(sT[xi][c0 + j]);
    unsigned short* dst = xt + ((((size_t)b * HH + y) * WW) + x0 + xi) * 64 + c0;
    *(bf16x8*)(dst)     = u.v[0];
    *(bf16x8*)(dst + 8) = u.v[1];
}

// ---------------- prep: weight fp32 [o][c][k] -> bf16 MFMA-B-fragment order ----------------
// wtp[ ((k*2+ks)*4+nt)*64*8 + l*8 + j ] = W[o=nt*16+(l&15)][c=ks*32+(l>>4)*8+j][k]
__global__ void wprep_kernel(const float* __restrict__ w, unsigned short* __restrict__ wtp) {
    int idx = blockIdx.x * 256 + threadIdx.x;
    if (idx >= COUT * CIN * K2) return;
    int j  = idx & 7;
    int l  = (idx >> 3) & 63;
    int nt = (idx >> 9) & 3;
    int ks = (idx >> 11) & 1;
    int k  = idx >> 12;
    int o  = nt * 16 + (l & 15);
    int c  = ks * 32 + (l >> 4) * 8 + j;
    wtp[idx] = f2bf(w[(o * CIN + c) * K2 + k]);
}

// ---------------- main ----------------
__launch_bounds__(256, 4)
__global__ void dcn_kernel(const unsigned short* __restrict__ xt,
                           const float* __restrict__ off,
                           const unsigned short* __restrict__ wtp,
                           float* __restrict__ out) {
    __shared__ unsigned short s_s[64 * 68];   // s[pix][c], row stride 136 B
    __shared__ float s_w[4 * 16 * 12];        // per-wave per-pixel {W00..W11, a0, a1, pad}

    const int tid = threadIdx.x;
    const int w   = tid >> 6;
    const int l   = tid & 63;

    int bid = blockIdx.x;
    bid = (bid & 7) * 256 + (bid >> 3);       // XCD swizzle: one batch per XCD
    const int b   = bid >> 8;
    const int t   = bid & 255;
    const int ty0 = (t >> 4) << 3;
    const int tx0 = (t & 15) << 3;

    const int g      = l >> 4;                // pixel subgroup within it
    const int lane16 = l & 15;

    f32x4 acc[4] = {{0,0,0,0},{0,0,0,0},{0,0,0,0},{0,0,0,0}};

    const float* offb = off + (size_t)b * (2 * K2) * HW;
    const unsigned short* xb = xt + (size_t)b * HW * 64;

    // phase-A pixel for this lane (16-way duplicated across groups; only l<16 writes)
    const int pixA = w * 16 + lane16;
    const int ypA  = ty0 + (pixA >> 3);
    const int xpA  = tx0 + (pixA & 7);
    const int offp = ypA * WW + xpA;

    float dyR = offb[offp];            // tap-0 offsets prefetched
    float dxR = offb[HW + offp];

    #pragma unroll
    for (int k = 0; k < K2; ++k) {
        const int kdy = k / 3 - 1, kdx = k % 3 - 1;

        // ---------- phase A: per-pixel bilinear params (computed once, shared via LDS) ----
        {
            float py = dyR + (float)(ypA + kdy);
            float px = dxR + (float)(xpA + kdx);
            float fy = floorf(py), fx = floorf(px);
            float wy = py - fy,    wx = px - fx;
            int y0  = (int)fy, x0i = (int)fx;
            int yc0 = min(max(y0,     0), HH - 1);
            int yc1 = min(max(y0 + 1, 0), HH - 1);
            float ay0 = (y0 >= 0  && y0 <= HH - 1) ? (1.f - wy) : 0.f;
            float ay1 = (y0 >= -1 && y0 <= HH - 2) ? wy         : 0.f;
            int   xL  = min(max(x0i, 0), WW - 2);
            float bx0 = (x0i >= 0  && x0i <= WW - 1) ? (1.f - wx) : 0.f;
            float bx1 = (x0i >= -1 && x0i <= WW - 2) ? wx         : 0.f;
            bool  sw  = (x0i != xL);
            float wxa = sw ? bx1 : bx0;
            float wxb = sw ? bx0 : bx1;
            f32x4 wv;
            wv[0] = ay0 * wxa; wv[1] = ay0 * wxb;
            wv[2] = ay1 * wxa; wv[3] = ay1 * wxb;
            int a0 = (yc0 * WW + xL) * 64;
            int a1 = (yc1 * WW + xL) * 64;
            if (l < 16) {
                float* wp = &s_w[pixA * 12];
                *(f32x4*)wp = wv;
                i32x2 av; av[0] = a0; av[1] = a1;
                *(i32x2*)(wp + 4) = av;
            }
        }

        // prefetch next tap's offsets (latency hidden behind phase B + MFMA)
        if (k < K2 - 1) {
            dyR = offb[(2 * (k + 1)    ) * HW + offp];
            dxR = offb[(2 * (k + 1) + 1) * HW + offp];
        }

        // ---------- phase B: batched param reads -> batched gathers -> packed interp ------
        f32x4 Wv[4];
        int   A0[4], A1[4];
        #pragma unroll
        for (int it = 0; it < 4; ++it) {
            const float* wp = &s_w[(w * 16 + it * 4 + g) * 12];
            Wv[it] = *(const f32x4*)wp;
            i32x2 av = *(const i32x2*)(wp + 4);
            A0[it] = av[0]; A1[it] = av[1];
        }
        u16x4 C00[4], C01[4], C10[4], C11[4];
        #pragma unroll
        for (int it = 0; it < 4; ++it) {
            const unsigned short* p0 = xb + A0[it] + 4 * lane16;
            const unsigned short* p1 = xb + A1[it] + 4 * lane16;
            C00[it] = *(const u16x4*)p0;
            C01[it] = *(const u16x4*)(p0 + 64);
            C10[it] = *(const u16x4*)p1;
            C11[it] = *(const u16x4*)(p1 + 64);
        }
        // B fragments for this tap issued early too (consumed after interp)
        bf16x8 bv[2][4];
        #pragma unroll
        for (int ks = 0; ks < 2; ++ks)
            #pragma unroll
            for (int nt = 0; nt < 4; ++nt)
                bv[ks][nt] = *(const bf16x8*)(wtp + (((k * 2 + ks) * 4 + nt) * 64 + l) * 8);

        #pragma unroll
        for (int it = 0; it < 4; ++it) {
            union { u16x4 h; unsigned int d[2]; } c00, c01, c10, c11;
            c00.h = C00[it]; c01.h = C01[it]; c10.h = C10[it]; c11.h = C11[it];
            f32x2 v0 = up2(c00.d[0]) * Wv[it][0] + up2(c01.d[0]) * Wv[it][1]
                     + up2(c10.d[0]) * Wv[it][2] + up2(c11.d[0]) * Wv[it][3];
            f32x2 v1 = up2(c00.d[1]) * Wv[it][0] + up2(c01.d[1]) * Wv[it][1]
                     + up2(c10.d[1]) * Wv[it][2] + up2(c11.d[1]) * Wv[it][3];
            u16x4 r;
            r[0] = f2bf(v0[0]); r[1] = f2bf(v0[1]);
            r[2] = f2bf(v1[0]); r[3] = f2bf(v1[1]);
            *(u16x4*)(&s_s[(w * 16 + it * 4 + g) * 68 + 4 * lane16]) = r;
        }

        // ---------- MFMA phase (wave-local LDS rows; compiler inserts lgkm waits) ---------
        const int row = w * 16 + lane16;
        #pragma unroll
        for (int ks = 0; ks < 2; ++ks) {
            const unsigned short* ap = &s_s[row * 68 + ks * 32 + g * 8];
            union { u16x4 h[2]; bf16x8 v; } af;
            af.h[0] = *(const u16x4*)ap;
            af.h[1] = *(const u16x4*)(ap + 4);
            #pragma unroll
            for (int nt = 0; nt < 4; ++nt)
                acc[nt] = __builtin_amdgcn_mfma_f32_16x16x32_bf16(af.v, bv[ks][nt], acc[nt], 0, 0, 0);
        }
    }

    // epilogue: C/D layout col=lane&15 (=o), row=(lane>>4)*4+j (=pix)
    const int o_lane = l & 15;
    const int rq     = (l >> 4) * 4;
    #pragma unroll
    for (int nt = 0; nt < 4; ++nt) {
        const int o = nt * 16 + o_lane;
        #pragma unroll
        for (int j = 0; j < 4; ++j) {
            const int pix = w * 16 + rq + j;
            const int yy  = ty0 + (pix >> 3);
            const int xx  = tx0 + (pix & 7);
            out[(((size_t)b * COUT + o) * HH + yy) * WW + xx] = acc[nt][j];
        }
    }
}

// ---------------- fallback path (no xt room): R0 kernel ----------------
__global__ void wprep_fb(const float* __restrict__ w, unsigned short* __restrict__ wt) {
    int idx = blockIdx.x * 256 + threadIdx.x;
    if (idx >= COUT * CIN * K2) return;
    int o = idx / (CIN * K2);
    int r = idx % (CIN * K2);
    int k = r / CIN;
    int c = r % CIN;
    wt[idx] = f2bf(w[o * (CIN * K2) + c * K2 + k]);
}

__launch_bounds__(256)
__global__ void dcn_fb(const float* __restrict__ x, const float* __restrict__ off,
                       const unsigned short* __restrict__ wt, float* __restrict__ out) {
    __shared__ unsigned short s_s[64 * 66];
    const int tid = threadIdx.x;
    const int w = tid >> 6, l = tid & 63;
    const int bid = blockIdx.x;
    const int b = bid >> 8, t = bid & 255;
    const int ty0 = (t >> 4) << 3, tx0 = (t & 15) << 3;
    const int iy = l >> 3, ix = l & 7;
    const int ypix = ty0 + iy, xpix = tx0 + ix;
    f32x4 acc[4] = {{0,0,0,0},{0,0,0,0},{0,0,0,0},{0,0,0,0}};
    const int c0w = w * 16;
    for (int k = 0; k < K2; ++k) {
        float dy = off[(((b * (2*K2)) + 2*k    ) * HH + ypix) * WW + xpix];
        float dx = off[(((b * (2*K2)) + 2*k + 1) * HH + ypix) * WW + xpix];
        float py = dy + (float)(k / 3 + ypix - 1);
        float px = dx + (float)(k % 3 + xpix - 1);
        float fy = floorf(py), fx = floorf(px);
        float wy = py - fy, wx = px - fx;
        int y0 = (int)fy, x0 = (int)fx;
        int yc0 = min(max(y0, 0), HH-1), yc1 = min(max(y0+1, 0), HH-1);
        float ay0 = (y0 >= 0 && y0 <= HH-1) ? (1.f-wy) : 0.f;
        float ay1 = (y0 >= -1 && y0 <= HH-2) ? wy : 0.f;
        int xL = min(max(x0, 0), WW-2);
        float bx0 = (x0 >= 0 && x0 <= WW-1) ? (1.f-wx) : 0.f;
        float bx1 = (x0 >= -1 && x0 <= WW-2) ? wx : 0.f;
        bool sw = (x0 != xL);
        float wxa = sw ? bx1 : bx0, wxb = sw ? bx0 : bx1;
        float W0x = ay0*wxa, W0y = ay0*wxb, W1x = ay1*wxa, W1y = ay1*wxb;
        const float* r0 = x + ((b * CIN + c0w) * HH + yc0) * WW + xL;
        const float* r1 = x + ((b * CIN + c0w) * HH + yc1) * WW + xL;
        unsigned short* sd = &s_s[l * 66 + c0w];
        #pragma unroll
        for (int cc = 0; cc < 16; ++cc) {
            sd[cc] = f2bf(W0x*r0[0] + W0y*r0[1] + W1x*r1[0] + W1y*r1[1]);
            r0 += HH*WW; r1 += HH*WW;
        }
        __syncthreads();
        const int o_lane = l & 15, q = l >> 4;
        #pragma unroll
        for (int ks = 0; ks < 2; ++ks) {
            const int cb = ks*32 + q*8;
            const int row = w*16 + o_lane;
            const unsigned int* sp = (const unsigned int*)s_s;
            const int ib = row*33 + (cb >> 1);
            union { unsigned int u[4]; bf16x8 v; } af;
            af.u[0]=sp[ib]; af.u[1]=sp[ib+1]; af.u[2]=sp[ib+2]; af.u[3]=sp[ib+3];
            #pragma unroll
            for (int nt = 0; nt < 4; ++nt) {
                bf16x8 bfv = *(const bf16x8*)(wt + (nt*16 + o_lane) * (CIN*K2) + k*64 + cb);
                acc[nt] = __builtin_amdgcn_mfma_f32_16x16x32_bf16(af.v, bfv, acc[nt], 0, 0, 0);
            }
        }
        __syncthreads();
    }
    const int o_lane = l & 15, rq = (l >> 4) * 4;
    #pragma unroll
    for (int nt = 0; nt < 4; ++nt) {
        const int o = nt*16 + o_lane;
        #pragma unroll
        for (int j = 0; j < 4; ++j) {
            const int pix = w*16 + rq + j;
            out[(((size_t)b * COUT + o) * HH + ty0 + (pix>>3)) * WW + tx0 + (pix&7)] = acc[nt][j];
        }
    }
}

extern "C" void kernel_launch(void* const* d_in, const int* in_sizes, int n_in,
                              void* d_out, int out_size, void* d_ws, size_t ws_size,
                              hipStream_t stream) {
    const float* x   = (const float*)d_in[0];
    const float* off = (const float*)d_in[1];
    const float* wgt = (const float*)d_in[2];
    float* out = (float*)d_out;

    const size_t xt_bytes = (size_t)8 * HH * WW * 64 * sizeof(unsigned short); // 16 MiB
    const size_t wt_bytes = (size_t)COUT * CIN * K2 * sizeof(unsigned short);  // 72 KiB

    if (ws_size >= xt_bytes + wt_bytes) {
        unsigned short* xt  = (unsigned short*)d_ws;
        unsigned short* wtp = (unsigned short*)((char*)d_ws + xt_bytes);
        xprep_kernel<<<2048, 256, 0, stream>>>(x, xt);
        wprep_kernel<<<(COUT * CIN * K2 + 255) / 256, 256, 0, stream>>>(wgt, wtp);
        dcn_kernel<<<2048, 256, 0, stream>>>(xt, off, wtp, out);
    } else {
        unsigned short* wt = (unsigned short*)d_ws;
        wprep_fb<<<(COUT * CIN * K2 + 255) / 256, 256, 0, stream>>>(wgt, wt);
        dcn_fb<<<2048, 256, 0, stream>>>(x, off, wt, out);
    }
}